// Round 1
// baseline (910.391 us; speedup 1.0000x reference)
//
#include <hip/hip_runtime.h>
#include <hip/hip_bf16.h>
#include <math.h>

// FastRPModel: out[e] = sigmoid(intercept - ||emb[idx_i[e]] - emb[idx_j[e]]||^2 / D)
// where emb[n,d] = sum_{p,k} softmax_k(fw)[p,k] * feats[p,k,n,d]
//
// Fused design: one 64-lane wave per edge; lane = d (D == 64).
// Each (p,k,node) row is a coalesced 256 B wave load. 24 row loads per edge.
// Nominal gather traffic 614 MB < streaming two-pass 880 MB, and duplicate
// node reads are served by L2/L3.

constexpr int Pp = 4;
constexpr int Kk = 3;
constexpr int Nn = 250000;
constexpr int Dd = 64;

__global__ __launch_bounds__(256) void fastrp_edge_kernel(
    const float* __restrict__ feats,      // [P,K,N,D]
    const float* __restrict__ fw,         // [P,K]
    const float* __restrict__ intercept,  // [1]
    const int*   __restrict__ idx_i,      // [E]
    const int*   __restrict__ idx_j,      // [E]
    float*       __restrict__ out,        // [E]
    int E)
{
    const int wave = (int)((blockIdx.x * (size_t)blockDim.x + threadIdx.x) >> 6);
    const int lane = threadIdx.x & 63;
    if (wave >= E) return;

    // --- softmax over K for each p (12 scalars, computed redundantly; L1-cached) ---
    float w[Pp * Kk];
    #pragma unroll
    for (int p = 0; p < Pp; ++p) {
        float e[Kk];
        float m = -INFINITY;
        #pragma unroll
        for (int k = 0; k < Kk; ++k) {
            e[k] = fw[p * Kk + k];
            m = fmaxf(m, e[k]);
        }
        float s = 0.0f;
        #pragma unroll
        for (int k = 0; k < Kk; ++k) {
            e[k] = __expf(e[k] - m);
            s += e[k];
        }
        const float inv = 1.0f / s;
        #pragma unroll
        for (int k = 0; k < Kk; ++k) w[p * Kk + k] = e[k] * inv;
    }

    const long long i = (long long)idx_i[wave];
    const long long j = (long long)idx_j[wave];

    // --- gather + weighted accumulate; lane owns dimension d = lane ---
    float zi = 0.0f, zj = 0.0f;
    #pragma unroll
    for (int pk = 0; pk < Pp * Kk; ++pk) {
        const float* base = feats + (size_t)pk * Nn * Dd;
        const float ai = base[i * Dd + lane];
        const float aj = base[j * Dd + lane];
        zi = fmaf(w[pk], ai, zi);
        zj = fmaf(w[pk], aj, zj);
    }

    float diff = zi - zj;
    float v = diff * diff;

    // --- 64-lane butterfly reduction ---
    #pragma unroll
    for (int off = 32; off > 0; off >>= 1) {
        v += __shfl_xor(v, off, 64);
    }

    if (lane == 0) {
        const float logit = intercept[0] - v * (1.0f / Dd);
        out[wave] = 1.0f / (1.0f + __expf(-logit));
    }
}

extern "C" void kernel_launch(void* const* d_in, const int* in_sizes, int n_in,
                              void* d_out, int out_size, void* d_ws, size_t ws_size,
                              hipStream_t stream) {
    const float* feats     = (const float*)d_in[0];
    const float* fw        = (const float*)d_in[1];
    const float* intercept = (const float*)d_in[2];
    const int*   idx_i     = (const int*)d_in[3];
    const int*   idx_j     = (const int*)d_in[4];
    float*       out       = (float*)d_out;

    const int E = in_sizes[3];

    const int block = 256;                 // 4 waves per block
    const int waves_per_block = block / 64;
    const int grid = (E + waves_per_block - 1) / waves_per_block;

    fastrp_edge_kernel<<<grid, block, 0, stream>>>(feats, fw, intercept,
                                                   idx_i, idx_j, out, E);
}